// Round 6
// baseline (252.861 us; speedup 1.0000x reference)
//
#include <hip/hip_runtime.h>
#include <hip/hip_bf16.h>

// ---------------------------------------------------------------------------
// Round-15 = Round-14 resubmit (container infra failure last round) + pad-init
// hygiene fix in the transpose side-block.
//   prep: r13 GEMM (X dbuf via global_load_lds) + binning + one block that
//     pre-transposes W2,W3 -> workspace (removes the bank-conflicted
//     stride-68 LDS transpose from every gather block).
//   gather_mlp_obs: 4-row-batched W2 matvec (each per-lane ds_read_b128 of
//     W2t reused 4x), int4 ssrc gather reads.
//   gather_mlp_task_pool: 2-row-batched W3 matvec, int4 ssrc reads.
// ---------------------------------------------------------------------------

#define CAP1 2816   // stage1: mean 2048/bucket, sigma~45  -> mean+17sigma
#define CAP2 5120   // stage2: mean 4096/bucket, sigma~64  -> mean+16sigma
#define GEMM_BLKS 640   // 128 goal + 512 obs (128-row tiles)

// --------------------- merged prep: GEMM + binning + transpose ------------
__global__ __launch_bounds__(256) void prep(
    const float* __restrict__ x_goal, const float* __restrict__ x_obs,
    const float* __restrict__ W, float* __restrict__ xg1,
    float* __restrict__ obs,
    const int* __restrict__ go_src, const int* __restrict__ go_dst,
    const int* __restrict__ ot_src, const int* __restrict__ ot_dst,
    int* __restrict__ gcur1, int* __restrict__ gcur2,
    int* __restrict__ pairs1, int* __restrict__ pairs2, int nblk1, int nblk2,
    const float* __restrict__ W2, const float* __restrict__ W3,
    float* __restrict__ w2t_g, float* __restrict__ w3t_g)
{
    __shared__ float smem[8192];         // 32 KB union (Xs dbuf | hist/cur)
    const int tid = threadIdx.x;

    if (blockIdx.x < GEMM_BLKS) {
        // -- 4x8 register GEMM: X dbuf-staged via global_load_lds, W via L1 --
        const float* X;
        float* O;
        int row0;
        if (blockIdx.x < 128) { X = x_goal; O = xg1; row0 = blockIdx.x * 128; }
        else                  { X = x_obs;  O = obs; row0 = (blockIdx.x - 128) * 128; }
        const int c0 = (tid & 7) * 8;
        const int trow = tid >> 3;       // 0..31
        const int r0 = trow * 4;
        const int swz = trow & 7;
        const int w = tid >> 6;          // wave 0..3
        const int lane = tid & 63;
        const int srow = w * 32 + (lane >> 3);      // + m*8
        const int skbx = lane & 7;

        float acc[4][8];
        #pragma unroll
        for (int i = 0; i < 4; ++i)
            #pragma unroll
            for (int j = 0; j < 8; ++j) acc[i][j] = 0.f;

        float* bufA = smem;              // [128*32] 16 KB
        float* bufB = smem + 4096;       // [128*32] 16 KB

        auto stage = [&](float* buf, int k0) {
            #pragma unroll
            for (int m = 0; m < 4; ++m) {
                int row = srow + m * 8;
                int kg = skbx ^ ((row >> 2) & 7);
                const float* gp = X + (size_t)(row0 + row) * 128 + k0 + kg * 4;
                __builtin_amdgcn_global_load_lds(
                    (const __attribute__((address_space(1))) unsigned int*)gp,
                    (__attribute__((address_space(3))) unsigned int*)
                        (buf + (w * 4 + m) * 256),
                    16, 0, 0);
            }
        };

        stage(bufA, 0);
        __syncthreads();                 // drain prologue stage

        float* cur = bufA;
        float* nxt = bufB;
        for (int kc = 0; kc < 4; ++kc) {
            const int k0 = kc * 32;
            if (kc < 3) stage(nxt, k0 + 32);   // async prefetch next tile
            #pragma unroll 2
            for (int kb = 0; kb < 8; ++kb) {
                float4 xv[4];
                #pragma unroll
                for (int i = 0; i < 4; ++i)
                    xv[i] = *(const float4*)(cur + (r0 + i) * 32 + ((kb ^ swz) << 2));
                #pragma unroll
                for (int kk = 0; kk < 4; ++kk) {
                    const float* wp = W + (size_t)(k0 + kb * 4 + kk) * 64 + c0;
                    float4 w0 = *(const float4*)(wp);
                    float4 w1 = *(const float4*)(wp + 4);
                    #pragma unroll
                    for (int i = 0; i < 4; ++i) {
                        float xk = (kk == 0) ? xv[i].x : (kk == 1) ? xv[i].y
                                 : (kk == 2) ? xv[i].z : xv[i].w;
                        acc[i][0] = fmaf(xk, w0.x, acc[i][0]);
                        acc[i][1] = fmaf(xk, w0.y, acc[i][1]);
                        acc[i][2] = fmaf(xk, w0.z, acc[i][2]);
                        acc[i][3] = fmaf(xk, w0.w, acc[i][3]);
                        acc[i][4] = fmaf(xk, w1.x, acc[i][4]);
                        acc[i][5] = fmaf(xk, w1.y, acc[i][5]);
                        acc[i][6] = fmaf(xk, w1.z, acc[i][6]);
                        acc[i][7] = fmaf(xk, w1.w, acc[i][7]);
                    }
                }
            }
            __syncthreads();             // drains nxt's loads (landed under compute)
            float* t = cur; cur = nxt; nxt = t;
        }
        #pragma unroll
        for (int i = 0; i < 4; ++i) {
            float4 o0; o0.x = acc[i][0]; o0.y = acc[i][1]; o0.z = acc[i][2]; o0.w = acc[i][3];
            float4 o1; o1.x = acc[i][4]; o1.y = acc[i][5]; o1.z = acc[i][6]; o1.w = acc[i][7];
            float* p = O + (size_t)(row0 + r0 + i) * 64 + c0;
            *(float4*)p = o0;
            *(float4*)(p + 4) = o1;
        }
    } else if (blockIdx.x < GEMM_BLKS + nblk1 + nblk2) {
        // ----------------------- coarse binning ----------------------------
        int* hist = (int*)smem;          // [512]
        int* cur  = (int*)smem + 512;    // [512]
        const int blk2 = blockIdx.x - GEMM_BLKS;
        const bool s1 = blk2 < nblk1;
        const int* src = s1 ? go_src : ot_src;
        const int* dst = s1 ? go_dst : ot_dst;
        int* gcur  = s1 ? gcur1 : gcur2;
        int* pairs = s1 ? pairs1 : pairs2;
        const int bsh  = s1 ? 7 : 5;
        const int rowm = s1 ? 127 : 31;
        const int nb   = s1 ? 512 : 256;
        const int cap  = s1 ? CAP1 : CAP2;
        const int blk  = s1 ? blk2 : blk2 - nblk1;

        for (int i = tid; i < nb; i += 256) hist[i] = 0;
        __syncthreads();
        const int base = blk * 4096;
        const int4* d4 = (const int4*)(dst + base);
        const int4* s4 = (const int4*)(src + base);
        int4 dv[4];
        #pragma unroll
        for (int k = 0; k < 4; ++k) {
            dv[k] = d4[k * 256 + tid];
            atomicAdd(&hist[dv[k].x >> bsh], 1);
            atomicAdd(&hist[dv[k].y >> bsh], 1);
            atomicAdd(&hist[dv[k].z >> bsh], 1);
            atomicAdd(&hist[dv[k].w >> bsh], 1);
        }
        __syncthreads();
        for (int i = tid; i < nb; i += 256)
            cur[i] = atomicAdd(&gcur[i], hist[i]);   // reserve contiguous run
        __syncthreads();
        #pragma unroll
        for (int k = 0; k < 4; ++k) {
            int4 sv = s4[k * 256 + tid];
            int d, s, b, p;
            d = dv[k].x; s = sv.x; b = d >> bsh; p = atomicAdd(&cur[b], 1);
            if (p < cap) pairs[(size_t)b * cap + p] = ((d & rowm) << 17) | s;
            d = dv[k].y; s = sv.y; b = d >> bsh; p = atomicAdd(&cur[b], 1);
            if (p < cap) pairs[(size_t)b * cap + p] = ((d & rowm) << 17) | s;
            d = dv[k].z; s = sv.z; b = d >> bsh; p = atomicAdd(&cur[b], 1);
            if (p < cap) pairs[(size_t)b * cap + p] = ((d & rowm) << 17) | s;
            d = dv[k].w; s = sv.w; b = d >> bsh; p = atomicAdd(&cur[b], 1);
            if (p < cap) pairs[(size_t)b * cap + p] = ((d & rowm) << 17) | s;
        }
    } else {
        // ------------- one-time W2/W3 transpose into workspace -------------
        // write the FULL padded 4352-entry buffers (pads zeroed) so gather
        // kernels never read uninitialized workspace.
        for (int i = tid; i < 4352; i += 256) {
            int c = i / 68, k = i % 68;
            float v2 = (k < 64) ? W2[k * 64 + c] : 0.f;
            float v3 = (k < 64) ? W3[k * 64 + c] : 0.f;
            w2t_g[i] = v2;
            w3t_g[i] = v3;
        }
    }
}

// ------------- stage-1 gather + fused obs MLP (4-row batched) -------------
__global__ __launch_bounds__(1024) void gather_mlp_obs(
    const int* __restrict__ pairs, const int* __restrict__ cnt,
    const float* __restrict__ xg1, const float* __restrict__ obs,
    const float* __restrict__ b1, const float* __restrict__ w2t_g,
    const float* __restrict__ b2, float* __restrict__ x1)
{
    constexpr int ROWS = 128;
    __shared__ __align__(16) int ssrc[CAP1];
    __shared__ int offs[ROWS + 1];
    __shared__ int rcnt[ROWS];
    __shared__ __align__(16) float W2t[64 * 68];   // pre-transposed copy
    __shared__ __align__(16) float hb[16 * 4 * 64];  // 16 KB: 4 rows per wave
    const int tid = threadIdx.x;
    const int b = blockIdx.x;

    // coalesced copy of pre-transposed W2
    #pragma unroll
    for (int i = tid; i < 4352; i += 1024) W2t[i] = w2t_g[i];
    if (tid < ROWS) rcnt[tid] = 0;
    __syncthreads();
    int n = cnt[b];
    if (n > CAP1) n = CAP1;
    const int* bp = pairs + (size_t)b * CAP1;

    // 1) histogram, caching packed edges in registers (<=3 per thread)
    int e0 = -1, e1 = -1, e2 = -1;
    {
        int i = tid;
        if (i < n) {
            e0 = bp[i]; atomicAdd(&rcnt[e0 >> 17], 1); i += 1024;
            if (i < n) {
                e1 = bp[i]; atomicAdd(&rcnt[e1 >> 17], 1); i += 1024;
                if (i < n) { e2 = bp[i]; atomicAdd(&rcnt[e2 >> 17], 1); }
            }
        }
    }
    __syncthreads();
    // 2) wave-0 shfl scan (2 elems/lane), rcnt becomes the scatter cursor
    if (tid < 64) {
        int v0 = rcnt[2 * tid], v1 = rcnt[2 * tid + 1];
        int s = v0 + v1;
        #pragma unroll
        for (int d = 1; d < 64; d <<= 1) {
            int t = __shfl_up(s, d);
            if (tid >= d) s += t;
        }
        int ex = s - v0 - v1;
        offs[2 * tid] = ex;
        offs[2 * tid + 1] = ex + v0;
        rcnt[2 * tid] = ex;
        rcnt[2 * tid + 1] = ex + v0;
        if (tid == 63) offs[ROWS] = s;
    }
    __syncthreads();
    // 3) scatter src ids into row-sorted order (register-cached edges)
    if (e0 >= 0) { int p = atomicAdd(&rcnt[e0 >> 17], 1); ssrc[p] = e0 & 0x1FFFF; }
    if (e1 >= 0) { int p = atomicAdd(&rcnt[e1 >> 17], 1); ssrc[p] = e1 & 0x1FFFF; }
    if (e2 >= 0) { int p = atomicAdd(&rcnt[e2 >> 17], 1); ssrc[p] = e2 & 0x1FFFF; }
    __syncthreads();
    // 4) 4-row groups: gather + stage h, then one batched W2-matvec pass
    const int wv = tid >> 6;
    const int lane = tid & 63;
    const float bb1 = b1[lane];
    const float bb2 = b2[lane];
    float* hpg = hb + wv * 256;
    const float4* h40 = (const float4*)hpg;
    const float4* wrow = (const float4*)(W2t + lane * 68);
    #pragma unroll
    for (int g = 0; g < 2; ++g) {
        const int rbase = wv + g * 64;
        #pragma unroll
        for (int j = 0; j < 4; ++j) {
            int r = rbase + j * 16;
            int beg = offs[r], end = offs[r + 1];
            float a0 = 0.f, a1 = 0.f, a2 = 0.f, a3 = 0.f;
            int e = beg;
            for (; e < end && (e & 3); ++e)
                a0 += xg1[(size_t)ssrc[e] * 64 + lane];
            for (; e + 4 <= end; e += 4) {
                int4 ss = *(const int4*)(ssrc + e);
                a0 += xg1[(size_t)ss.x * 64 + lane];
                a1 += xg1[(size_t)ss.y * 64 + lane];
                a2 += xg1[(size_t)ss.z * 64 + lane];
                a3 += xg1[(size_t)ss.w * 64 + lane];
            }
            for (; e < end; ++e)
                a0 += xg1[(size_t)ssrc[e] * 64 + lane];
            size_t gi = (((size_t)b * ROWS) + r) * 64 + lane;
            float acc = (a0 + a1) + (a2 + a3) + obs[gi];
            hpg[j * 64 + lane] = fmaxf(acc + bb1, 0.f);   // same-wave stage
        }
        float acc4[4] = {bb2, bb2, bb2, bb2};
        #pragma unroll 4
        for (int kc = 0; kc < 16; ++kc) {
            float4 wv4 = wrow[kc];       // per-lane b128, reused 4x
            #pragma unroll
            for (int j = 0; j < 4; ++j) {
                float4 hv = h40[j * 16 + kc];   // wave-uniform broadcast b128
                acc4[j] = fmaf(hv.x, wv4.x, acc4[j]);
                acc4[j] = fmaf(hv.y, wv4.y, acc4[j]);
                acc4[j] = fmaf(hv.z, wv4.z, acc4[j]);
                acc4[j] = fmaf(hv.w, wv4.w, acc4[j]);
            }
        }
        #pragma unroll
        for (int j = 0; j < 4; ++j) {
            size_t gi = (((size_t)b * ROWS) + rbase + j * 16) * 64 + lane;
            x1[gi] = fmaxf(acc4[j], 0.f);
        }
    }
}

// ------------- stage-2 gather + fused task MLP + pool + critic ------------
// One 1024-thread WG per bucket of 32 task rows == one graph.
__global__ __launch_bounds__(1024) void gather_mlp_task_pool(
    const int* __restrict__ pairs, const int* __restrict__ cnt,
    const float* __restrict__ x1, const float* __restrict__ x_task,
    const float* __restrict__ w3t_g, const float* __restrict__ b3,
    const float* __restrict__ W4, const float* __restrict__ b4,
    const float* __restrict__ Wc1, const float* __restrict__ bc1,
    const float* __restrict__ Wc2, const float* __restrict__ bc2,
    float* __restrict__ out)
{
    constexpr int ROWS = 32;
    __shared__ __align__(16) int ssrc[CAP2];
    __shared__ int offs[ROWS + 1];
    __shared__ int rcnt[ROWS];
    __shared__ __align__(16) float W3t[64 * 68];
    __shared__ __align__(16) float hb[16 * 2 * 64];  // 8 KB: 2 rows per wave
    __shared__ float xrow[ROWS];
    const int tid = threadIdx.x;
    const int b = blockIdx.x;

    #pragma unroll
    for (int i = tid; i < 4352; i += 1024) W3t[i] = w3t_g[i];
    if (tid < ROWS) rcnt[tid] = 0;
    __syncthreads();
    int n = cnt[b];
    if (n > CAP2) n = CAP2;
    const int* bp = pairs + (size_t)b * CAP2;

    // 1) histogram with register-cached packed edges (<=5 per thread)
    int e0 = -1, e1 = -1, e2 = -1, e3 = -1, e4 = -1;
    {
        int i = tid;
        if (i < n) { e0 = bp[i]; atomicAdd(&rcnt[e0 >> 17], 1); i += 1024;
        if (i < n) { e1 = bp[i]; atomicAdd(&rcnt[e1 >> 17], 1); i += 1024;
        if (i < n) { e2 = bp[i]; atomicAdd(&rcnt[e2 >> 17], 1); i += 1024;
        if (i < n) { e3 = bp[i]; atomicAdd(&rcnt[e3 >> 17], 1); i += 1024;
        if (i < n) { e4 = bp[i]; atomicAdd(&rcnt[e4 >> 17], 1); } } } } }
    }
    __syncthreads();
    // 2) wave-0 shfl scan over 32 rows
    if (tid < 32) {
        int v = rcnt[tid];
        int s = v;
        #pragma unroll
        for (int d = 1; d < 32; d <<= 1) {
            int t = __shfl_up(s, d);
            if (tid >= d) s += t;
        }
        int ex = s - v;
        offs[tid] = ex;
        rcnt[tid] = ex;
        if (tid == 31) offs[ROWS] = s;
    }
    __syncthreads();
    // 3) scatter
    if (e0 >= 0) { int p = atomicAdd(&rcnt[e0 >> 17], 1); ssrc[p] = e0 & 0x1FFFF; }
    if (e1 >= 0) { int p = atomicAdd(&rcnt[e1 >> 17], 1); ssrc[p] = e1 & 0x1FFFF; }
    if (e2 >= 0) { int p = atomicAdd(&rcnt[e2 >> 17], 1); ssrc[p] = e2 & 0x1FFFF; }
    if (e3 >= 0) { int p = atomicAdd(&rcnt[e3 >> 17], 1); ssrc[p] = e3 & 0x1FFFF; }
    if (e4 >= 0) { int p = atomicAdd(&rcnt[e4 >> 17], 1); ssrc[p] = e4 & 0x1FFFF; }
    __syncthreads();

    // 4) two rows per wave: gather both, then one batched W3-matvec pass
    const int wv = tid >> 6;
    const int lane = tid & 63;
    const float bb3 = b3[lane];
    const float w4l = W4[lane];
    const float b4c = b4[0];
    float* hpg = hb + wv * 128;
    const float4* h40 = (const float4*)hpg;
    const float4* wrow = (const float4*)(W3t + lane * 68);
    #pragma unroll
    for (int half = 0; half < 2; ++half) {
        const int r = wv + half * 16;
        const int row = b * ROWS + r;
        int beg = offs[r], end = offs[r + 1];
        float a0 = 0.f, a1 = 0.f, a2 = 0.f, a3 = 0.f;
        float a4 = 0.f, a5 = 0.f, a6 = 0.f, a7 = 0.f;
        int e = beg;
        for (; e < end && (e & 3); ++e)
            a0 += x1[(size_t)ssrc[e] * 64 + lane];
        for (; e + 8 <= end; e += 8) {
            int4 s0 = *(const int4*)(ssrc + e);
            int4 s1 = *(const int4*)(ssrc + e + 4);
            a0 += x1[(size_t)s0.x * 64 + lane];
            a1 += x1[(size_t)s0.y * 64 + lane];
            a2 += x1[(size_t)s0.z * 64 + lane];
            a3 += x1[(size_t)s0.w * 64 + lane];
            a4 += x1[(size_t)s1.x * 64 + lane];
            a5 += x1[(size_t)s1.y * 64 + lane];
            a6 += x1[(size_t)s1.z * 64 + lane];
            a7 += x1[(size_t)s1.w * 64 + lane];
        }
        for (; e + 4 <= end; e += 4) {
            int4 s0 = *(const int4*)(ssrc + e);
            a0 += x1[(size_t)s0.x * 64 + lane];
            a1 += x1[(size_t)s0.y * 64 + lane];
            a2 += x1[(size_t)s0.z * 64 + lane];
            a3 += x1[(size_t)s0.w * 64 + lane];
        }
        for (; e < end; ++e)
            a0 += x1[(size_t)ssrc[e] * 64 + lane];
        float t = ((a0 + a1) + (a2 + a3)) + ((a4 + a5) + (a6 + a7))
                + x_task[(size_t)row * 64 + lane];
        hpg[half * 64 + lane] = t;               // same-wave stage (no relu)
    }
    {
        float acc2[2] = {bb3, bb3};
        #pragma unroll 4
        for (int kc = 0; kc < 16; ++kc) {
            float4 wv4 = wrow[kc];               // reused for both rows
            float4 hv0 = h40[kc];
            float4 hv1 = h40[16 + kc];
            acc2[0] = fmaf(hv0.x, wv4.x, acc2[0]);
            acc2[0] = fmaf(hv0.y, wv4.y, acc2[0]);
            acc2[0] = fmaf(hv0.z, wv4.z, acc2[0]);
            acc2[0] = fmaf(hv0.w, wv4.w, acc2[0]);
            acc2[1] = fmaf(hv1.x, wv4.x, acc2[1]);
            acc2[1] = fmaf(hv1.y, wv4.y, acc2[1]);
            acc2[1] = fmaf(hv1.z, wv4.z, acc2[1]);
            acc2[1] = fmaf(hv1.w, wv4.w, acc2[1]);
        }
        #pragma unroll
        for (int half = 0; half < 2; ++half) {
            float p = fmaxf(acc2[half], 0.f) * w4l;
            p += __shfl_xor(p, 1);
            p += __shfl_xor(p, 2);
            p += __shfl_xor(p, 4);
            p += __shfl_xor(p, 8);
            p += __shfl_xor(p, 16);
            p += __shfl_xor(p, 32);
            if (lane == 0) xrow[wv + half * 16] = p + b4c;
        }
    }
    __syncthreads();
    // 5) pool + critic for this graph
    if (tid == 0) {
        float mx = -1e30f, sm = 0.f;
        #pragma unroll
        for (int i = 0; i < ROWS; ++i) {
            float v = xrow[i];
            mx = fmaxf(mx, v);
            sm += v;
        }
        float mn = sm * (1.f / 32.f);
        float o = bc2[0];
        #pragma unroll
        for (int j = 0; j < 8; ++j) {
            float t = fmaxf(mx * Wc1[j] + mn * Wc1[8 + j] + bc1[j], 0.f);
            o = fmaf(t, Wc2[j], o);
        }
        out[b] = o;
    }
}

extern "C" void kernel_launch(void* const* d_in, const int* in_sizes, int n_in,
                              void* d_out, int out_size, void* d_ws, size_t ws_size,
                              hipStream_t stream)
{
    const float* x_goal = (const float*)d_in[0];
    const float* x_obs  = (const float*)d_in[1];
    const float* x_task = (const float*)d_in[2];
    const int* go_src = (const int*)d_in[3];
    const int* go_dst = (const int*)d_in[4];
    const int* ot_src = (const int*)d_in[5];
    const int* ot_dst = (const int*)d_in[6];
    const float* W1  = (const float*)d_in[8];
    const float* b1  = (const float*)d_in[9];
    const float* W2  = (const float*)d_in[10];
    const float* b2  = (const float*)d_in[11];
    const float* W3  = (const float*)d_in[12];
    const float* b3  = (const float*)d_in[13];
    const float* W4  = (const float*)d_in[14];
    const float* b4  = (const float*)d_in[15];
    const float* Wc1 = (const float*)d_in[16];
    const float* bc1 = (const float*)d_in[17];
    const float* Wc2 = (const float*)d_in[18];
    const float* bc2 = (const float*)d_in[19];
    float* out = (float*)d_out;

    const int N_OBS = 65536, N_GOAL = 16384;
    const int E1 = in_sizes[3], E2 = in_sizes[5];
    const int NB1 = 512, NB2 = 256;

    // workspace (~47 MB of 256 MiB)
    char* w = (char*)d_ws;
    float* obs    = (float*)w;  w += (size_t)N_OBS * 64 * 4;        // 16 MB
    float* x1     = (float*)w;  w += (size_t)N_OBS * 64 * 4;        // 16 MB
    float* xg1    = (float*)w;  w += (size_t)N_GOAL * 64 * 4;       //  4 MB
    int*   pairs1 = (int*)w;    w += (size_t)NB1 * CAP1 * 4;        //  5.8 MB
    int*   pairs2 = (int*)w;    w += (size_t)NB2 * CAP2 * 4;        //  5.2 MB
    int*   gcur1  = (int*)w;    w += NB1 * 4;
    int*   gcur2  = (int*)w;    w += NB2 * 4;
    float* w2t_g  = (float*)w;  w += 64 * 68 * 4;                   // 17.4 KB
    float* w3t_g  = (float*)w;  w += 64 * 68 * 4;                   // 17.4 KB

    hipMemsetAsync(gcur1, 0, (NB1 + NB2) * 4, stream);

    const int nblk1 = E1 / 4096;
    const int nblk2 = E2 / 4096;
    prep<<<GEMM_BLKS + nblk1 + nblk2 + 1, 256, 0, stream>>>(
        x_goal, x_obs, W1, xg1, obs,
        go_src, go_dst, ot_src, ot_dst, gcur1, gcur2, pairs1, pairs2,
        nblk1, nblk2, W2, W3, w2t_g, w3t_g);
    gather_mlp_obs<<<NB1, 1024, 0, stream>>>(pairs1, gcur1, xg1, obs, b1, w2t_g, b2, x1);
    gather_mlp_task_pool<<<NB2, 1024, 0, stream>>>(pairs2, gcur2, x1, x_task,
                                                   w3t_g, b3, W4, b4,
                                                   Wc1, bc1, Wc2, bc2, out);
}

// Round 7
// 226.016 us; speedup vs baseline: 1.1188x; 1.1188x over previous
//
#include <hip/hip_runtime.h>
#include <hip/hip_bf16.h>

// ---------------------------------------------------------------------------
// Round-16 structure:
//   prep: unchanged r13/r15 (GEMM X-dbuf via global_load_lds + binning +
//     one-time W2/W3 transpose block).
//   gather kernels: REVERT r14's row-batched matvec (regressed obs 49->60us;
//     counters showed latency-bound, not LDS-pipe-bound).  Back to the r13
//     fused per-row loop (gather -> same-wave LDS stage -> matvec), keeping
//     the two safe r14 pieces: pre-transposed W2t/W3t from workspace (no
//     bank-conflicted stride-68 transpose) and int4 ssrc reads.  New:
//     8 accumulator chains in obs (2x memory-level parallelism per row) and
//     the row-base load (obs/x_task) issued BEFORE the edge loop so its
//     latency hides under the gather.
// ---------------------------------------------------------------------------

#define CAP1 2816   // stage1: mean 2048/bucket, sigma~45  -> mean+17sigma
#define CAP2 5120   // stage2: mean 4096/bucket, sigma~64  -> mean+16sigma
#define GEMM_BLKS 640   // 128 goal + 512 obs (128-row tiles)

// --------------------- merged prep: GEMM + binning + transpose ------------
__global__ __launch_bounds__(256) void prep(
    const float* __restrict__ x_goal, const float* __restrict__ x_obs,
    const float* __restrict__ W, float* __restrict__ xg1,
    float* __restrict__ obs,
    const int* __restrict__ go_src, const int* __restrict__ go_dst,
    const int* __restrict__ ot_src, const int* __restrict__ ot_dst,
    int* __restrict__ gcur1, int* __restrict__ gcur2,
    int* __restrict__ pairs1, int* __restrict__ pairs2, int nblk1, int nblk2,
    const float* __restrict__ W2, const float* __restrict__ W3,
    float* __restrict__ w2t_g, float* __restrict__ w3t_g)
{
    __shared__ float smem[8192];         // 32 KB union (Xs dbuf | hist/cur)
    const int tid = threadIdx.x;

    if (blockIdx.x < GEMM_BLKS) {
        // -- 4x8 register GEMM: X dbuf-staged via global_load_lds, W via L1 --
        const float* X;
        float* O;
        int row0;
        if (blockIdx.x < 128) { X = x_goal; O = xg1; row0 = blockIdx.x * 128; }
        else                  { X = x_obs;  O = obs; row0 = (blockIdx.x - 128) * 128; }
        const int c0 = (tid & 7) * 8;
        const int trow = tid >> 3;       // 0..31
        const int r0 = trow * 4;
        const int swz = trow & 7;
        const int w = tid >> 6;          // wave 0..3
        const int lane = tid & 63;
        const int srow = w * 32 + (lane >> 3);      // + m*8
        const int skbx = lane & 7;

        float acc[4][8];
        #pragma unroll
        for (int i = 0; i < 4; ++i)
            #pragma unroll
            for (int j = 0; j < 8; ++j) acc[i][j] = 0.f;

        float* bufA = smem;              // [128*32] 16 KB
        float* bufB = smem + 4096;       // [128*32] 16 KB

        auto stage = [&](float* buf, int k0) {
            #pragma unroll
            for (int m = 0; m < 4; ++m) {
                int row = srow + m * 8;
                int kg = skbx ^ ((row >> 2) & 7);
                const float* gp = X + (size_t)(row0 + row) * 128 + k0 + kg * 4;
                __builtin_amdgcn_global_load_lds(
                    (const __attribute__((address_space(1))) unsigned int*)gp,
                    (__attribute__((address_space(3))) unsigned int*)
                        (buf + (w * 4 + m) * 256),
                    16, 0, 0);
            }
        };

        stage(bufA, 0);
        __syncthreads();                 // drain prologue stage

        float* cur = bufA;
        float* nxt = bufB;
        for (int kc = 0; kc < 4; ++kc) {
            const int k0 = kc * 32;
            if (kc < 3) stage(nxt, k0 + 32);   // async prefetch next tile
            #pragma unroll 2
            for (int kb = 0; kb < 8; ++kb) {
                float4 xv[4];
                #pragma unroll
                for (int i = 0; i < 4; ++i)
                    xv[i] = *(const float4*)(cur + (r0 + i) * 32 + ((kb ^ swz) << 2));
                #pragma unroll
                for (int kk = 0; kk < 4; ++kk) {
                    const float* wp = W + (size_t)(k0 + kb * 4 + kk) * 64 + c0;
                    float4 w0 = *(const float4*)(wp);
                    float4 w1 = *(const float4*)(wp + 4);
                    #pragma unroll
                    for (int i = 0; i < 4; ++i) {
                        float xk = (kk == 0) ? xv[i].x : (kk == 1) ? xv[i].y
                                 : (kk == 2) ? xv[i].z : xv[i].w;
                        acc[i][0] = fmaf(xk, w0.x, acc[i][0]);
                        acc[i][1] = fmaf(xk, w0.y, acc[i][1]);
                        acc[i][2] = fmaf(xk, w0.z, acc[i][2]);
                        acc[i][3] = fmaf(xk, w0.w, acc[i][3]);
                        acc[i][4] = fmaf(xk, w1.x, acc[i][4]);
                        acc[i][5] = fmaf(xk, w1.y, acc[i][5]);
                        acc[i][6] = fmaf(xk, w1.z, acc[i][6]);
                        acc[i][7] = fmaf(xk, w1.w, acc[i][7]);
                    }
                }
            }
            __syncthreads();             // drains nxt's loads (landed under compute)
            float* t = cur; cur = nxt; nxt = t;
        }
        #pragma unroll
        for (int i = 0; i < 4; ++i) {
            float4 o0; o0.x = acc[i][0]; o0.y = acc[i][1]; o0.z = acc[i][2]; o0.w = acc[i][3];
            float4 o1; o1.x = acc[i][4]; o1.y = acc[i][5]; o1.z = acc[i][6]; o1.w = acc[i][7];
            float* p = O + (size_t)(row0 + r0 + i) * 64 + c0;
            *(float4*)p = o0;
            *(float4*)(p + 4) = o1;
        }
    } else if (blockIdx.x < GEMM_BLKS + nblk1 + nblk2) {
        // ----------------------- coarse binning ----------------------------
        int* hist = (int*)smem;          // [512]
        int* cur  = (int*)smem + 512;    // [512]
        const int blk2 = blockIdx.x - GEMM_BLKS;
        const bool s1 = blk2 < nblk1;
        const int* src = s1 ? go_src : ot_src;
        const int* dst = s1 ? go_dst : ot_dst;
        int* gcur  = s1 ? gcur1 : gcur2;
        int* pairs = s1 ? pairs1 : pairs2;
        const int bsh  = s1 ? 7 : 5;
        const int rowm = s1 ? 127 : 31;
        const int nb   = s1 ? 512 : 256;
        const int cap  = s1 ? CAP1 : CAP2;
        const int blk  = s1 ? blk2 : blk2 - nblk1;

        for (int i = tid; i < nb; i += 256) hist[i] = 0;
        __syncthreads();
        const int base = blk * 4096;
        const int4* d4 = (const int4*)(dst + base);
        const int4* s4 = (const int4*)(src + base);
        int4 dv[4];
        #pragma unroll
        for (int k = 0; k < 4; ++k) {
            dv[k] = d4[k * 256 + tid];
            atomicAdd(&hist[dv[k].x >> bsh], 1);
            atomicAdd(&hist[dv[k].y >> bsh], 1);
            atomicAdd(&hist[dv[k].z >> bsh], 1);
            atomicAdd(&hist[dv[k].w >> bsh], 1);
        }
        __syncthreads();
        for (int i = tid; i < nb; i += 256)
            cur[i] = atomicAdd(&gcur[i], hist[i]);   // reserve contiguous run
        __syncthreads();
        #pragma unroll
        for (int k = 0; k < 4; ++k) {
            int4 sv = s4[k * 256 + tid];
            int d, s, b, p;
            d = dv[k].x; s = sv.x; b = d >> bsh; p = atomicAdd(&cur[b], 1);
            if (p < cap) pairs[(size_t)b * cap + p] = ((d & rowm) << 17) | s;
            d = dv[k].y; s = sv.y; b = d >> bsh; p = atomicAdd(&cur[b], 1);
            if (p < cap) pairs[(size_t)b * cap + p] = ((d & rowm) << 17) | s;
            d = dv[k].z; s = sv.z; b = d >> bsh; p = atomicAdd(&cur[b], 1);
            if (p < cap) pairs[(size_t)b * cap + p] = ((d & rowm) << 17) | s;
            d = dv[k].w; s = sv.w; b = d >> bsh; p = atomicAdd(&cur[b], 1);
            if (p < cap) pairs[(size_t)b * cap + p] = ((d & rowm) << 17) | s;
        }
    } else {
        // ------------- one-time W2/W3 transpose into workspace -------------
        for (int i = tid; i < 4352; i += 256) {
            int c = i / 68, k = i % 68;
            float v2 = (k < 64) ? W2[k * 64 + c] : 0.f;
            float v3 = (k < 64) ? W3[k * 64 + c] : 0.f;
            w2t_g[i] = v2;
            w3t_g[i] = v3;
        }
    }
}

// ------------- stage-1 gather + fused obs MLP (r13 fused row loop) --------
__global__ __launch_bounds__(1024) void gather_mlp_obs(
    const int* __restrict__ pairs, const int* __restrict__ cnt,
    const float* __restrict__ xg1, const float* __restrict__ obs,
    const float* __restrict__ b1, const float* __restrict__ w2t_g,
    const float* __restrict__ b2, float* __restrict__ x1)
{
    constexpr int ROWS = 128;
    __shared__ __align__(16) int ssrc[CAP1];
    __shared__ int offs[ROWS + 1];
    __shared__ int rcnt[ROWS];
    __shared__ __align__(16) float W2t[64 * 68];   // pre-transposed copy
    __shared__ __align__(16) float hb[16 * 64];
    const int tid = threadIdx.x;
    const int b = blockIdx.x;

    // coalesced copy of pre-transposed W2
    #pragma unroll
    for (int i = tid; i < 4352; i += 1024) W2t[i] = w2t_g[i];
    if (tid < ROWS) rcnt[tid] = 0;
    __syncthreads();
    int n = cnt[b];
    if (n > CAP1) n = CAP1;
    const int* bp = pairs + (size_t)b * CAP1;

    // 1) histogram, caching packed edges in registers (<=3 per thread)
    int e0 = -1, e1 = -1, e2 = -1;
    {
        int i = tid;
        if (i < n) {
            e0 = bp[i]; atomicAdd(&rcnt[e0 >> 17], 1); i += 1024;
            if (i < n) {
                e1 = bp[i]; atomicAdd(&rcnt[e1 >> 17], 1); i += 1024;
                if (i < n) { e2 = bp[i]; atomicAdd(&rcnt[e2 >> 17], 1); }
            }
        }
    }
    __syncthreads();
    // 2) wave-0 shfl scan (2 elems/lane), rcnt becomes the scatter cursor
    if (tid < 64) {
        int v0 = rcnt[2 * tid], v1 = rcnt[2 * tid + 1];
        int s = v0 + v1;
        #pragma unroll
        for (int d = 1; d < 64; d <<= 1) {
            int t = __shfl_up(s, d);
            if (tid >= d) s += t;
        }
        int ex = s - v0 - v1;
        offs[2 * tid] = ex;
        offs[2 * tid + 1] = ex + v0;
        rcnt[2 * tid] = ex;
        rcnt[2 * tid + 1] = ex + v0;
        if (tid == 63) offs[ROWS] = s;
    }
    __syncthreads();
    // 3) scatter src ids into row-sorted order (register-cached edges)
    if (e0 >= 0) { int p = atomicAdd(&rcnt[e0 >> 17], 1); ssrc[p] = e0 & 0x1FFFF; }
    if (e1 >= 0) { int p = atomicAdd(&rcnt[e1 >> 17], 1); ssrc[p] = e1 & 0x1FFFF; }
    if (e2 >= 0) { int p = atomicAdd(&rcnt[e2 >> 17], 1); ssrc[p] = e2 & 0x1FFFF; }
    __syncthreads();
    // 4) per-row: 8-chain gather (early base load) + fused MLP
    const int wv = tid >> 6;
    const int lane = tid & 63;
    const float bb1 = b1[lane];
    const float bb2 = b2[lane];
    float* hp = hb + wv * 64;
    const float4* h4 = (const float4*)hp;
    const float4* wrow = (const float4*)(W2t + lane * 68);
    for (int r = wv; r < ROWS; r += 16) {
        int beg = offs[r], end = offs[r + 1];
        size_t gi = (((size_t)b * ROWS) + r) * 64 + lane;
        float base = obs[gi];            // issued early: hides under gather
        float a0 = 0.f, a1 = 0.f, a2 = 0.f, a3 = 0.f;
        float a4 = 0.f, a5 = 0.f, a6 = 0.f, a7 = 0.f;
        int e = beg;
        for (; e < end && (e & 3); ++e)
            a0 += xg1[(size_t)ssrc[e] * 64 + lane];
        for (; e + 8 <= end; e += 8) {
            int4 s0 = *(const int4*)(ssrc + e);
            int4 s1 = *(const int4*)(ssrc + e + 4);
            a0 += xg1[(size_t)s0.x * 64 + lane];
            a1 += xg1[(size_t)s0.y * 64 + lane];
            a2 += xg1[(size_t)s0.z * 64 + lane];
            a3 += xg1[(size_t)s0.w * 64 + lane];
            a4 += xg1[(size_t)s1.x * 64 + lane];
            a5 += xg1[(size_t)s1.y * 64 + lane];
            a6 += xg1[(size_t)s1.z * 64 + lane];
            a7 += xg1[(size_t)s1.w * 64 + lane];
        }
        for (; e + 4 <= end; e += 4) {
            int4 s0 = *(const int4*)(ssrc + e);
            a0 += xg1[(size_t)s0.x * 64 + lane];
            a1 += xg1[(size_t)s0.y * 64 + lane];
            a2 += xg1[(size_t)s0.z * 64 + lane];
            a3 += xg1[(size_t)s0.w * 64 + lane];
        }
        for (; e < end; ++e)
            a0 += xg1[(size_t)ssrc[e] * 64 + lane];
        float acc = ((a0 + a1) + (a2 + a3)) + ((a4 + a5) + (a6 + a7)) + base;
        hp[lane] = fmaxf(acc + bb1, 0.f);                // same-wave stage
        float a = bb2;
        #pragma unroll 8
        for (int kc = 0; kc < 16; ++kc) {
            float4 hv = h4[kc];          // wave-uniform broadcast b128
            float4 wv4 = wrow[kc];       // per-lane b128
            a = fmaf(hv.x, wv4.x, a);
            a = fmaf(hv.y, wv4.y, a);
            a = fmaf(hv.z, wv4.z, a);
            a = fmaf(hv.w, wv4.w, a);
        }
        x1[gi] = fmaxf(a, 0.f);
    }
}

// ------------- stage-2 gather + fused task MLP + pool + critic ------------
// One 1024-thread WG per bucket of 32 task rows == one graph.
__global__ __launch_bounds__(1024) void gather_mlp_task_pool(
    const int* __restrict__ pairs, const int* __restrict__ cnt,
    const float* __restrict__ x1, const float* __restrict__ x_task,
    const float* __restrict__ w3t_g, const float* __restrict__ b3,
    const float* __restrict__ W4, const float* __restrict__ b4,
    const float* __restrict__ Wc1, const float* __restrict__ bc1,
    const float* __restrict__ Wc2, const float* __restrict__ bc2,
    float* __restrict__ out)
{
    constexpr int ROWS = 32;
    __shared__ __align__(16) int ssrc[CAP2];
    __shared__ int offs[ROWS + 1];
    __shared__ int rcnt[ROWS];
    __shared__ __align__(16) float W3t[64 * 68];
    __shared__ __align__(16) float hb[16 * 64];
    __shared__ float xrow[ROWS];
    const int tid = threadIdx.x;
    const int b = blockIdx.x;

    #pragma unroll
    for (int i = tid; i < 4352; i += 1024) W3t[i] = w3t_g[i];
    if (tid < ROWS) rcnt[tid] = 0;
    __syncthreads();
    int n = cnt[b];
    if (n > CAP2) n = CAP2;
    const int* bp = pairs + (size_t)b * CAP2;

    // 1) histogram with register-cached packed edges (<=5 per thread)
    int e0 = -1, e1 = -1, e2 = -1, e3 = -1, e4 = -1;
    {
        int i = tid;
        if (i < n) { e0 = bp[i]; atomicAdd(&rcnt[e0 >> 17], 1); i += 1024;
        if (i < n) { e1 = bp[i]; atomicAdd(&rcnt[e1 >> 17], 1); i += 1024;
        if (i < n) { e2 = bp[i]; atomicAdd(&rcnt[e2 >> 17], 1); i += 1024;
        if (i < n) { e3 = bp[i]; atomicAdd(&rcnt[e3 >> 17], 1); i += 1024;
        if (i < n) { e4 = bp[i]; atomicAdd(&rcnt[e4 >> 17], 1); } } } } }
    }
    __syncthreads();
    // 2) wave-0 shfl scan over 32 rows
    if (tid < 32) {
        int v = rcnt[tid];
        int s = v;
        #pragma unroll
        for (int d = 1; d < 32; d <<= 1) {
            int t = __shfl_up(s, d);
            if (tid >= d) s += t;
        }
        int ex = s - v;
        offs[tid] = ex;
        rcnt[tid] = ex;
        if (tid == 31) offs[ROWS] = s;
    }
    __syncthreads();
    // 3) scatter
    if (e0 >= 0) { int p = atomicAdd(&rcnt[e0 >> 17], 1); ssrc[p] = e0 & 0x1FFFF; }
    if (e1 >= 0) { int p = atomicAdd(&rcnt[e1 >> 17], 1); ssrc[p] = e1 & 0x1FFFF; }
    if (e2 >= 0) { int p = atomicAdd(&rcnt[e2 >> 17], 1); ssrc[p] = e2 & 0x1FFFF; }
    if (e3 >= 0) { int p = atomicAdd(&rcnt[e3 >> 17], 1); ssrc[p] = e3 & 0x1FFFF; }
    if (e4 >= 0) { int p = atomicAdd(&rcnt[e4 >> 17], 1); ssrc[p] = e4 & 0x1FFFF; }
    __syncthreads();

    // 4) two rows per wave: 8-chain gather (early base) + fused task MLP
    const int wv = tid >> 6;
    const int lane = tid & 63;
    const float bb3 = b3[lane];
    const float w4l = W4[lane];
    const float b4c = b4[0];
    float* hp = hb + wv * 64;
    const float4* h4 = (const float4*)hp;
    const float4* wrow = (const float4*)(W3t + lane * 68);
    #pragma unroll
    for (int half = 0; half < 2; ++half) {
        const int r = wv + half * 16;
        const int row = b * ROWS + r;
        int beg = offs[r], end = offs[r + 1];
        float base = x_task[(size_t)row * 64 + lane];   // early issue
        float a0 = 0.f, a1 = 0.f, a2 = 0.f, a3 = 0.f;
        float a4 = 0.f, a5 = 0.f, a6 = 0.f, a7 = 0.f;
        int e = beg;
        for (; e < end && (e & 3); ++e)
            a0 += x1[(size_t)ssrc[e] * 64 + lane];
        for (; e + 8 <= end; e += 8) {
            int4 s0 = *(const int4*)(ssrc + e);
            int4 s1 = *(const int4*)(ssrc + e + 4);
            a0 += x1[(size_t)s0.x * 64 + lane];
            a1 += x1[(size_t)s0.y * 64 + lane];
            a2 += x1[(size_t)s0.z * 64 + lane];
            a3 += x1[(size_t)s0.w * 64 + lane];
            a4 += x1[(size_t)s1.x * 64 + lane];
            a5 += x1[(size_t)s1.y * 64 + lane];
            a6 += x1[(size_t)s1.z * 64 + lane];
            a7 += x1[(size_t)s1.w * 64 + lane];
        }
        for (; e + 4 <= end; e += 4) {
            int4 s0 = *(const int4*)(ssrc + e);
            a0 += x1[(size_t)s0.x * 64 + lane];
            a1 += x1[(size_t)s0.y * 64 + lane];
            a2 += x1[(size_t)s0.z * 64 + lane];
            a3 += x1[(size_t)s0.w * 64 + lane];
        }
        for (; e < end; ++e)
            a0 += x1[(size_t)ssrc[e] * 64 + lane];
        float t = ((a0 + a1) + (a2 + a3)) + ((a4 + a5) + (a6 + a7)) + base;
        hp[lane] = t;                            // same-wave stage (no relu)
        float a = bb3;
        #pragma unroll 8
        for (int kc = 0; kc < 16; ++kc) {
            float4 hv = h4[kc];
            float4 wv4 = wrow[kc];
            a = fmaf(hv.x, wv4.x, a);
            a = fmaf(hv.y, wv4.y, a);
            a = fmaf(hv.z, wv4.z, a);
            a = fmaf(hv.w, wv4.w, a);
        }
        float p = fmaxf(a, 0.f) * w4l;
        p += __shfl_xor(p, 1);
        p += __shfl_xor(p, 2);
        p += __shfl_xor(p, 4);
        p += __shfl_xor(p, 8);
        p += __shfl_xor(p, 16);
        p += __shfl_xor(p, 32);
        if (lane == 0) xrow[r] = p + b4c;
    }
    __syncthreads();
    // 5) pool + critic for this graph
    if (tid == 0) {
        float mx = -1e30f, sm = 0.f;
        #pragma unroll
        for (int i = 0; i < ROWS; ++i) {
            float v = xrow[i];
            mx = fmaxf(mx, v);
            sm += v;
        }
        float mn = sm * (1.f / 32.f);
        float o = bc2[0];
        #pragma unroll
        for (int j = 0; j < 8; ++j) {
            float t = fmaxf(mx * Wc1[j] + mn * Wc1[8 + j] + bc1[j], 0.f);
            o = fmaf(t, Wc2[j], o);
        }
        out[b] = o;
    }
}

extern "C" void kernel_launch(void* const* d_in, const int* in_sizes, int n_in,
                              void* d_out, int out_size, void* d_ws, size_t ws_size,
                              hipStream_t stream)
{
    const float* x_goal = (const float*)d_in[0];
    const float* x_obs  = (const float*)d_in[1];
    const float* x_task = (const float*)d_in[2];
    const int* go_src = (const int*)d_in[3];
    const int* go_dst = (const int*)d_in[4];
    const int* ot_src = (const int*)d_in[5];
    const int* ot_dst = (const int*)d_in[6];
    const float* W1  = (const float*)d_in[8];
    const float* b1  = (const float*)d_in[9];
    const float* W2  = (const float*)d_in[10];
    const float* b2  = (const float*)d_in[11];
    const float* W3  = (const float*)d_in[12];
    const float* b3  = (const float*)d_in[13];
    const float* W4  = (const float*)d_in[14];
    const float* b4  = (const float*)d_in[15];
    const float* Wc1 = (const float*)d_in[16];
    const float* bc1 = (const float*)d_in[17];
    const float* Wc2 = (const float*)d_in[18];
    const float* bc2 = (const float*)d_in[19];
    float* out = (float*)d_out;

    const int N_OBS = 65536, N_GOAL = 16384;
    const int E1 = in_sizes[3], E2 = in_sizes[5];
    const int NB1 = 512, NB2 = 256;

    // workspace (~47 MB of 256 MiB)
    char* w = (char*)d_ws;
    float* obs    = (float*)w;  w += (size_t)N_OBS * 64 * 4;        // 16 MB
    float* x1     = (float*)w;  w += (size_t)N_OBS * 64 * 4;        // 16 MB
    float* xg1    = (float*)w;  w += (size_t)N_GOAL * 64 * 4;       //  4 MB
    int*   pairs1 = (int*)w;    w += (size_t)NB1 * CAP1 * 4;        //  5.8 MB
    int*   pairs2 = (int*)w;    w += (size_t)NB2 * CAP2 * 4;        //  5.2 MB
    int*   gcur1  = (int*)w;    w += NB1 * 4;
    int*   gcur2  = (int*)w;    w += NB2 * 4;
    float* w2t_g  = (float*)w;  w += 64 * 68 * 4;                   // 17.4 KB
    float* w3t_g  = (float*)w;  w += 64 * 68 * 4;                   // 17.4 KB

    hipMemsetAsync(gcur1, 0, (NB1 + NB2) * 4, stream);

    const int nblk1 = E1 / 4096;
    const int nblk2 = E2 / 4096;
    prep<<<GEMM_BLKS + nblk1 + nblk2 + 1, 256, 0, stream>>>(
        x_goal, x_obs, W1, xg1, obs,
        go_src, go_dst, ot_src, ot_dst, gcur1, gcur2, pairs1, pairs2,
        nblk1, nblk2, W2, W3, w2t_g, w3t_g);
    gather_mlp_obs<<<NB1, 1024, 0, stream>>>(pairs1, gcur1, xg1, obs, b1, w2t_g, b2, x1);
    gather_mlp_task_pool<<<NB2, 1024, 0, stream>>>(pairs2, gcur2, x1, x_task,
                                                   w3t_g, b3, W4, b4,
                                                   Wc1, bc1, Wc2, bc2, out);
}